// Round 15
// baseline (212.030 us; speedup 1.0000x reference)
//
#include <hip/hip_runtime.h>
#include <math.h>

#define NN 4096
#define NPART 8              // XCD partitions (blockIdx%8 -> XCD round-robin)
#define PROWS 512            // rows (cols) per partition = NN/NPART
#define NCHK 128             // input chunks
#define SEGCAP 512           // per-(partition,chunk) segment capacity (mean 320, +11 sigma)
#define HS 4096              // phase-2 LDS hash slots (load ~31%)
#define GR 16                // rows (cols) per phase-2 block

// mysign(|v|) - 0.5 with reference-faithful overflow: e=inf -> NaN
__device__ __forceinline__ float smh(float v) {
    float e = expf(6.0f * fabsf(v));
    return 0.5f * (e - 1.0f) / (e + 1.0f);
}

// Phase 1: block (p = blockIdx%8, chunk = blockIdx/8) filters chunk records
// whose row (resp. col) lies in partition p into an LDS stash, then flushes
// coalesced into its PRIVATE segment. Plain-store count; no global atomics,
// no zero-init anywhere. Record tag carries (c,r,isC).
__global__ __launch_bounds__(256) void seg_k(
    const long* __restrict__ edges, const float* __restrict__ weights,
    const float* __restrict__ stat, const long* __restrict__ edges_c,
    const float* __restrict__ grdt, float4* __restrict__ rowseg,
    float4* __restrict__ colseg, int* __restrict__ rowcnt,
    int* __restrict__ colcnt, int E, int EC) {
    __shared__ float4 rstash[SEGCAP], cstash[SEGCAP];
    __shared__ int nr, nc;
    const int tid = threadIdx.x;
    if (tid == 0) { nr = 0; nc = 0; }
    __syncthreads();
    const int p = blockIdx.x & (NPART - 1);
    const int chunk = blockIdx.x >> 3;
    const int total = E + EC;
    const int csz = (total + NCHK - 1) / NCHK;
    const int lo = chunk * csz;
    const int hi = min(lo + csz, total);
    for (int i = lo + tid; i < hi; i += 256) {
        long e; int isC;
        if (i < E) { e = edges[i]; isC = 0; }
        else { e = edges_c[i - E]; isC = 1; }
        int r = (int)e;              // little-endian: x = low 32 bits
        int c = (int)(e >> 32);
        bool rowHit = (r >> 9) == p;
        bool colHit = (c >> 9) == p;
        if (!rowHit && !colHit) continue;
        float4 rec;
        rec.x = __int_as_float((c << 13) | (r << 1) | isC);
        if (isC) { rec.y = grdt[i - E]; rec.z = 0.f; }
        else { rec.y = stat[i]; rec.z = weights[i]; }
        rec.w = 0.f;
        if (rowHit) {
            int pos = atomicAdd(&nr, 1);           // LDS counter
            if (pos < SEGCAP) rstash[pos] = rec;
        }
        if (colHit) {
            int pos = atomicAdd(&nc, 1);
            if (pos < SEGCAP) cstash[pos] = rec;
        }
    }
    __syncthreads();
    const size_t segbase = (size_t)blockIdx.x * SEGCAP;
    int mr = min(nr, SEGCAP), mc = min(nc, SEGCAP);
    for (int i = tid; i < mr; i += 256) rowseg[segbase + i] = rstash[i];
    for (int i = tid; i < mc; i += 256) colseg[segbase + i] = cstash[i];
    if (tid == 0) { rowcnt[blockIdx.x] = mr; colcnt[blockIdx.x] = mc; }
}

// Phase 2a: block owns 16 cols of its partition. Streams the partition's
// col-segments (XCD-local L2), LDS-hash coalesces duplicate cells
// (scatter-add semantics like the reference), sweeps v = B*(A-1)+A*W:
// g += v, nin += smh(v); good = clip(g/Nin,-1,1) NaN-propagating,
// Nin baseline 2048 (mysign(0)=0.5 per zero cell).
__global__ __launch_bounds__(256) void colgood_k(
    const float4* __restrict__ colseg, const int* __restrict__ colcnt,
    float* __restrict__ good_buf, float* __restrict__ good_out) {
    __shared__ int hkey[HS];
    __shared__ float hA[HS], hW[HS], hB[HS];
    __shared__ int scnt[NCHK];
    __shared__ float a1[GR], a2[GR];
    const int tid = threadIdx.x;
    const int p = blockIdx.x & (NPART - 1);
    const int gi = blockIdx.x >> 3;            // 0..31
    const int cb = p * PROWS + gi * GR;
    for (int i = tid; i < HS; i += 256) {
        hkey[i] = -1; hA[i] = 0.f; hW[i] = 0.f; hB[i] = 0.f;
    }
    if (tid < NCHK) scnt[tid] = colcnt[(tid << 3) | p];
    if (tid < GR) { a1[tid] = 0.f; a2[tid] = 0.f; }
    __syncthreads();
    for (int chunk = 0; chunk < NCHK; ++chunk) {
        const int n = scnt[chunk];
        const float4* sp = colseg + (size_t)((chunk << 3) | p) * SEGCAP;
        for (int i = tid; i < n; i += 256) {
            float4 rec = sp[i];
            int ct = __float_as_int(rec.x);
            int c = ct >> 13;
            unsigned d = (unsigned)(c - cb);
            if (d >= GR) continue;             // not one of my 16 cols
            int r = (ct >> 1) & 4095;
            int key = ((int)d << 12) | r;
            int slot = (int)(((unsigned)key * 2654435761u) >> 20) & (HS - 1);
            while (true) {
                int prev = atomicCAS(&hkey[slot], -1, key);
                if (prev == -1 || prev == key) break;
                slot = (slot + 1) & (HS - 1);
            }
            if (ct & 1) {
                atomicAdd(&hB[slot], rec.y);
            } else {
                atomicAdd(&hA[slot], rec.y);
                atomicAdd(&hW[slot], rec.z);
            }
        }
    }
    __syncthreads();
#pragma unroll
    for (int k = 0; k < HS / 256; ++k) {       // 16 slots/thread
        int s = k * 256 + tid;
        int key = hkey[s];
        if (key != -1) {
            float a = hA[s], w = hW[s], b = hB[s];
            float v = b * (a - 1.0f) + a * w;
            if (v != 0.0f) {                   // zero cells: 0 to all sums
                int lc = key >> 12;
                atomicAdd(&a1[lc], smh(v));    // NaN propagates like ref
                atomicAdd(&a2[lc], v);         // g (column sum)
            }
        }
    }
    __syncthreads();
    if (tid < GR) {
        float Nin = 2048.0f + a1[tid];
        float gd = 1.0f;
        if (Nin != 0.0f) {
            float x = a2[tid] / Nin;
            gd = x < -1.0f ? -1.0f : (x > 1.0f ? 1.0f : x);  // NaN stays NaN
        }
        good_buf[cb + tid] = gd;
        good_out[cb + tid] = gd;
    }
}

// Phase 2b: block owns 16 rows; same streaming hash; fair computed inline
// at the sweep. f += 1 - |v - good[c]|/2 over v != 0;
// fair = clip(f/Nout, 0, 1). Last block does the targets gsum.
__global__ __launch_bounds__(256) void rowfair_k(
    const float4* __restrict__ rowseg, const int* __restrict__ rowcnt,
    const float* __restrict__ good_buf, const int* __restrict__ targets,
    int T, float* __restrict__ out) {
    if (blockIdx.x < NN / GR) {
        __shared__ int hkey[HS];
        __shared__ float hA[HS], hW[HS], hB[HS];
        __shared__ int scnt[NCHK];
        __shared__ float a1[GR], a2[GR];
        const int tid = threadIdx.x;
        const int p = blockIdx.x & (NPART - 1);
        const int gi = blockIdx.x >> 3;
        const int rb = p * PROWS + gi * GR;
        for (int i = tid; i < HS; i += 256) {
            hkey[i] = -1; hA[i] = 0.f; hW[i] = 0.f; hB[i] = 0.f;
        }
        if (tid < NCHK) scnt[tid] = rowcnt[(tid << 3) | p];
        if (tid < GR) { a1[tid] = 0.f; a2[tid] = 0.f; }
        __syncthreads();
        for (int chunk = 0; chunk < NCHK; ++chunk) {
            const int n = scnt[chunk];
            const float4* sp = rowseg + (size_t)((chunk << 3) | p) * SEGCAP;
            for (int i = tid; i < n; i += 256) {
                float4 rec = sp[i];
                int ct = __float_as_int(rec.x);
                int r = (ct >> 1) & 4095;
                unsigned d = (unsigned)(r - rb);
                if (d >= GR) continue;         // not one of my 16 rows
                int c = ct >> 13;
                int key = ((int)d << 12) | c;
                int slot = (int)(((unsigned)key * 2654435761u) >> 20) & (HS - 1);
                while (true) {
                    int prev = atomicCAS(&hkey[slot], -1, key);
                    if (prev == -1 || prev == key) break;
                    slot = (slot + 1) & (HS - 1);
                }
                if (ct & 1) {
                    atomicAdd(&hB[slot], rec.y);
                } else {
                    atomicAdd(&hA[slot], rec.y);
                    atomicAdd(&hW[slot], rec.z);
                }
            }
        }
        __syncthreads();
#pragma unroll
        for (int k = 0; k < HS / 256; ++k) {   // 16 slots/thread
            int s = k * 256 + tid;
            int key = hkey[s];
            if (key != -1) {
                float a = hA[s], w = hW[s], b = hB[s];
                float v = b * (a - 1.0f) + a * w;
                if (v != 0.0f) {               // reference mask: V != 0
                    int lr = key >> 12;
                    atomicAdd(&a1[lr], smh(v));     // NaN propagates
                    atomicAdd(&a2[lr],
                              1.0f - 0.5f * fabsf(v - good_buf[key & 4095]));
                }
            }
        }
        __syncthreads();
        if (tid < GR) {
            float Nout = 2048.0f + a1[tid];
            float fair = 1.0f;
            if (Nout != 0.0f) {
                float x = a2[tid] / Nout;
                fair = x < 0.0f ? 0.0f : (x > 1.0f ? 1.0f : x);  // NaN stays
            }
            out[1 + rb + tid] = fair;
        }
    } else {
        float s = 0.f;
        for (int i = threadIdx.x; i < T; i += 256) {
            float gt = good_buf[targets[i]];
            s += (gt == gt) ? gt : 0.0f;       // NaN -> 0
        }
        for (int off = 32; off > 0; off >>= 1) s += __shfl_down(s, off, 64);
        __shared__ float lds[4];
        int lane = threadIdx.x & 63, w = threadIdx.x >> 6;
        if (lane == 0) lds[w] = s;
        __syncthreads();
        if (threadIdx.x == 0) out[0] = lds[0] + lds[1] + lds[2] + lds[3];
    }
}

extern "C" void kernel_launch(void* const* d_in, const int* in_sizes, int n_in,
                              void* d_out, int out_size, void* d_ws, size_t ws_size,
                              hipStream_t stream) {
    const long*  edges   = (const long*)d_in[0];
    const float* weights = (const float*)d_in[1];
    const float* stat    = (const float*)d_in[2];
    const long*  edges_c = (const long*)d_in[3];
    const float* grdt    = (const float*)d_in[4];
    const int*   targets = (const int*)d_in[5];
    const int E  = in_sizes[1];
    const int EC = in_sizes[4];
    const int T  = in_sizes[5];
    float* out = (float*)d_out;

    int*    rowcnt   = (int*)d_ws;                            // 1024
    int*    colcnt   = rowcnt + NPART * NCHK;                 // 1024
    float*  good_buf = (float*)(colcnt + NPART * NCHK);       // NN
    float4* rowseg   = (float4*)(good_buf + NN);              // 1024*SEGCAP
    float4* colseg   = rowseg + (size_t)NPART * NCHK * SEGCAP;

    seg_k<<<NPART * NCHK, 256, 0, stream>>>(
        edges, weights, stat, edges_c, grdt, rowseg, colseg,
        rowcnt, colcnt, E, EC);

    colgood_k<<<NN / GR, 256, 0, stream>>>(colseg, colcnt, good_buf,
                                           out + 1 + NN);

    rowfair_k<<<NN / GR + 1, 256, 0, stream>>>(rowseg, rowcnt, good_buf,
                                               targets, T, out);
}

// Round 16
// 68.365 us; speedup vs baseline: 3.1015x; 3.1015x over previous
//
#include <hip/hip_runtime.h>
#include <math.h>

#define NN 4096
#define NPART 8              // XCD partitions (blockIdx%8 -> XCD round-robin)
#define NCHK 128             // phase-1 input chunks
#define SEGCAP 512           // per-(chunk,partition) segment cap (mean 320, +11 sigma)
#define NSUB 16              // groups handled per subsplit block (half of 32)
#define SUBCAP 160           // per-(block,group) stash cap (mean 80, +9 sigma)
#define GCAP 1536            // per-group segment cap (mean 1280, +7 sigma)
#define NGRP 256             // 16-row (16-col) groups per side
#define HS 2048              // phase-3 LDS hash slots (load ~62%)

// mysign(|v|) - 0.5 with reference-faithful overflow: e=inf -> NaN
__device__ __forceinline__ float smh(float v) {
    float e = expf(6.0f * fabsf(v));
    return 0.5f * (e - 1.0f) / (e + 1.0f);
}

// Phase 1 (measured ~12us in r15): block (p=blockIdx&7, chunk=blockIdx>>3)
// filters its chunk into LDS stashes, flushes coalesced to private segments,
// plain-stores counts. No global atomics, no zero-init. Block 0 also zeroes
// the phase-1.5 group counters (read only after this kernel completes).
__global__ __launch_bounds__(256) void seg_k(
    const long* __restrict__ edges, const float* __restrict__ weights,
    const float* __restrict__ stat, const long* __restrict__ edges_c,
    const float* __restrict__ grdt, float4* __restrict__ rowseg,
    float4* __restrict__ colseg, int* __restrict__ rowcnt,
    int* __restrict__ colcnt, int* __restrict__ gcnt, int E, int EC) {
    __shared__ float4 rstash[SEGCAP], cstash[SEGCAP];
    __shared__ int nr, nc;
    const int tid = threadIdx.x;
    if (blockIdx.x == 0)
        for (int i = tid; i < 2 * NGRP; i += 256) gcnt[i] = 0;
    if (tid == 0) { nr = 0; nc = 0; }
    __syncthreads();
    const int p = blockIdx.x & (NPART - 1);
    const int chunk = blockIdx.x >> 3;
    const int total = E + EC;
    const int csz = (total + NCHK - 1) / NCHK;
    const int lo = chunk * csz;
    const int hi = min(lo + csz, total);
    for (int i = lo + tid; i < hi; i += 256) {
        long e; int isC;
        if (i < E) { e = edges[i]; isC = 0; }
        else { e = edges_c[i - E]; isC = 1; }
        int r = (int)e;              // little-endian: x = low 32 bits
        int c = (int)(e >> 32);
        bool rowHit = (r >> 9) == p;
        bool colHit = (c >> 9) == p;
        if (!rowHit && !colHit) continue;
        float4 rec;
        rec.x = __int_as_float((c << 13) | (r << 1) | isC);
        if (isC) { rec.y = grdt[i - E]; rec.z = 0.f; }
        else { rec.y = stat[i]; rec.z = weights[i]; }
        rec.w = 0.f;
        if (rowHit) {
            int pos = atomicAdd(&nr, 1);           // LDS counter
            if (pos < SEGCAP) rstash[pos] = rec;
        }
        if (colHit) {
            int pos = atomicAdd(&nc, 1);
            if (pos < SEGCAP) cstash[pos] = rec;
        }
    }
    __syncthreads();
    const size_t segbase = (size_t)blockIdx.x * SEGCAP;
    int mr = min(nr, SEGCAP), mc = min(nc, SEGCAP);
    for (int i = tid; i < mr; i += 256) rowseg[segbase + i] = rstash[i];
    for (int i = tid; i < mc; i += 256) colseg[segbase + i] = cstash[i];
    if (tid == 0) { rowcnt[blockIdx.x] = mr; colcnt[blockIdx.x] = mc; }
}

// Phase 1.5: second split level. Block (side, half, rng, p) reads 8 of
// partition p's chunk-segments and re-splits into 16 per-group LDS stashes
// (16-row groups), then reserves space with ONE global atomicAdd per group
// (8K atomics total, contention-free) and flushes coalesced. XCD-local:
// blockIdx%8 == p, matching phase 1's writer XCD.
__global__ __launch_bounds__(256) void subsplit_k(
    const float4* __restrict__ rowseg, const float4* __restrict__ colseg,
    const int* __restrict__ rowcnt, const int* __restrict__ colcnt,
    int* __restrict__ gcnt, float4* __restrict__ subseg) {
    __shared__ float4 stash[NSUB][SUBCAP];
    __shared__ int sc[NSUB];
    __shared__ int bases[NSUB];
    const int tid = threadIdx.x;
    const int bi = blockIdx.x;
    const int p = bi & 7;
    const int rng = (bi >> 3) & 15;
    const int half = (bi >> 7) & 1;
    const int side = bi >> 8;            // 0 = row side, 1 = col side
    const float4* seg = side ? colseg : rowseg;
    const int* cnts = side ? colcnt : rowcnt;
    if (tid < NSUB) sc[tid] = 0;
    __syncthreads();
    const int sub0 = half * NSUB;        // first in-partition group handled
    for (int ch = rng * 8; ch < rng * 8 + 8; ++ch) {
        const int sidx = (ch << 3) | p;
        const int n = cnts[sidx];
        const float4* sp = seg + (size_t)sidx * SEGCAP;
        for (int i = tid; i < n; i += 256) {
            float4 rec = sp[i];
            int ct = __float_as_int(rec.x);
            int x = side ? (ct >> 13) : ((ct >> 1) & 4095);
            int sub = ((x >> 4) & 31) - sub0;
            if ((unsigned)sub < NSUB) {
                int pos = atomicAdd(&sc[sub], 1);     // LDS counter
                if (pos < SUBCAP) stash[sub][pos] = rec;
            }
        }
    }
    __syncthreads();
    if (tid < NSUB) {
        int c = min(sc[tid], SUBCAP);
        sc[tid] = c;
        int grp = p * 32 + sub0 + tid;   // == x>>4 for this group
        bases[tid] = atomicAdd(&gcnt[side * NGRP + grp], c);
    }
    __syncthreads();
    for (int s = 0; s < NSUB; ++s) {
        int grp = p * 32 + sub0 + s;
        size_t gb = (size_t)(side * NGRP + grp) * GCAP;
        int b0 = bases[s], n = sc[s];
        for (int i = tid; i < n; i += 256)
            if (b0 + i < GCAP) subseg[gb + b0 + i] = stash[s][i];
    }
}

// Phase 2a: block per 16-col group, reads EXACTLY its group's records
// (no amplification). LDS hash coalesces duplicate cells (scatter-add
// semantics like the reference); sweep v = B*(A-1)+A*W: g += v,
// nin += smh(v); good = clip(g/Nin,-1,1) NaN-propagating, Nin baseline
// 2048 (mysign(0)=0.5 per zero cell). XCD-local: blockIdx%8 = partition.
__global__ __launch_bounds__(256) void colgood_k(
    const float4* __restrict__ subseg, const int* __restrict__ gcnt,
    float* __restrict__ good_buf, float* __restrict__ good_out) {
    __shared__ int hkey[HS];
    __shared__ float hA[HS], hW[HS], hB[HS];
    __shared__ float a1[16], a2[16];
    const int tid = threadIdx.x;
    const int g = (blockIdx.x & 7) * 32 + (blockIdx.x >> 3);
    const int cb = g * 16;
    for (int i = tid; i < HS; i += 256) {
        hkey[i] = -1; hA[i] = 0.f; hW[i] = 0.f; hB[i] = 0.f;
    }
    if (tid < 16) { a1[tid] = 0.f; a2[tid] = 0.f; }
    __syncthreads();
    int n = gcnt[NGRP + g]; if (n > GCAP) n = GCAP;
    const float4* sp = subseg + (size_t)(NGRP + g) * GCAP;
    for (int i = tid; i < n; i += 256) {
        float4 rec = sp[i];
        int ct = __float_as_int(rec.x);
        int c = ct >> 13;
        int r = (ct >> 1) & 4095;
        int key = ((c - cb) << 12) | r;
        int slot = (int)(((unsigned)key * 2654435761u) >> 21) & (HS - 1);
        while (true) {
            int prev = atomicCAS(&hkey[slot], -1, key);
            if (prev == -1 || prev == key) break;
            slot = (slot + 1) & (HS - 1);
        }
        if (ct & 1) {
            atomicAdd(&hB[slot], rec.y);
        } else {
            atomicAdd(&hA[slot], rec.y);
            atomicAdd(&hW[slot], rec.z);
        }
    }
    __syncthreads();
#pragma unroll
    for (int k = 0; k < HS / 256; ++k) {       // 8 slots/thread
        int s = k * 256 + tid;
        int key = hkey[s];
        if (key != -1) {
            float a = hA[s], w = hW[s], b = hB[s];
            float v = b * (a - 1.0f) + a * w;
            if (v != 0.0f) {                   // zero cells: 0 to all sums
                int d = key >> 12;
                atomicAdd(&a1[d], smh(v));     // NaN propagates like ref
                atomicAdd(&a2[d], v);          // g (column sum)
            }
        }
    }
    __syncthreads();
    if (tid < 16) {
        float Nin = 2048.0f + a1[tid];
        float gd = 1.0f;
        if (Nin != 0.0f) {
            float x = a2[tid] / Nin;
            gd = x < -1.0f ? -1.0f : (x > 1.0f ? 1.0f : x);  // NaN stays NaN
        }
        good_buf[cb + tid] = gd;
        good_out[cb + tid] = gd;
    }
}

// Phase 2b: block per 16-row group; same hash; fair computed inline
// (good_buf final). f += 1 - |v - good[c]|/2 over v != 0;
// fair = clip(f/Nout, 0, 1). Last block does the targets gsum.
__global__ __launch_bounds__(256) void rowfair_k(
    const float4* __restrict__ subseg, const int* __restrict__ gcnt,
    const float* __restrict__ good_buf, const int* __restrict__ targets,
    int T, float* __restrict__ out) {
    if (blockIdx.x < NGRP) {
        __shared__ int hkey[HS];
        __shared__ float hA[HS], hW[HS], hB[HS];
        __shared__ float a1[16], a2[16];
        const int tid = threadIdx.x;
        const int g = (blockIdx.x & 7) * 32 + (blockIdx.x >> 3);
        const int rb = g * 16;
        for (int i = tid; i < HS; i += 256) {
            hkey[i] = -1; hA[i] = 0.f; hW[i] = 0.f; hB[i] = 0.f;
        }
        if (tid < 16) { a1[tid] = 0.f; a2[tid] = 0.f; }
        __syncthreads();
        int n = gcnt[g]; if (n > GCAP) n = GCAP;
        const float4* sp = subseg + (size_t)g * GCAP;
        for (int i = tid; i < n; i += 256) {
            float4 rec = sp[i];
            int ct = __float_as_int(rec.x);
            int c = ct >> 13;
            int r = (ct >> 1) & 4095;
            int key = ((r - rb) << 12) | c;
            int slot = (int)(((unsigned)key * 2654435761u) >> 21) & (HS - 1);
            while (true) {
                int prev = atomicCAS(&hkey[slot], -1, key);
                if (prev == -1 || prev == key) break;
                slot = (slot + 1) & (HS - 1);
            }
            if (ct & 1) {
                atomicAdd(&hB[slot], rec.y);
            } else {
                atomicAdd(&hA[slot], rec.y);
                atomicAdd(&hW[slot], rec.z);
            }
        }
        __syncthreads();
#pragma unroll
        for (int k = 0; k < HS / 256; ++k) {   // 8 slots/thread
            int s = k * 256 + tid;
            int key = hkey[s];
            if (key != -1) {
                float a = hA[s], w = hW[s], b = hB[s];
                float v = b * (a - 1.0f) + a * w;
                if (v != 0.0f) {               // reference mask: V != 0
                    int d = key >> 12;
                    atomicAdd(&a1[d], smh(v)); // NaN propagates
                    atomicAdd(&a2[d],
                              1.0f - 0.5f * fabsf(v - good_buf[key & 4095]));
                }
            }
        }
        __syncthreads();
        if (tid < 16) {
            float Nout = 2048.0f + a1[tid];
            float fair = 1.0f;
            if (Nout != 0.0f) {
                float x = a2[tid] / Nout;
                fair = x < 0.0f ? 0.0f : (x > 1.0f ? 1.0f : x);  // NaN stays
            }
            out[1 + rb + tid] = fair;
        }
    } else {
        float s = 0.f;
        for (int i = threadIdx.x; i < T; i += 256) {
            float gt = good_buf[targets[i]];
            s += (gt == gt) ? gt : 0.0f;       // NaN -> 0
        }
        for (int off = 32; off > 0; off >>= 1) s += __shfl_down(s, off, 64);
        __shared__ float lds[4];
        int lane = threadIdx.x & 63, w = threadIdx.x >> 6;
        if (lane == 0) lds[w] = s;
        __syncthreads();
        if (threadIdx.x == 0) out[0] = lds[0] + lds[1] + lds[2] + lds[3];
    }
}

extern "C" void kernel_launch(void* const* d_in, const int* in_sizes, int n_in,
                              void* d_out, int out_size, void* d_ws, size_t ws_size,
                              hipStream_t stream) {
    const long*  edges   = (const long*)d_in[0];
    const float* weights = (const float*)d_in[1];
    const float* stat    = (const float*)d_in[2];
    const long*  edges_c = (const long*)d_in[3];
    const float* grdt    = (const float*)d_in[4];
    const int*   targets = (const int*)d_in[5];
    const int E  = in_sizes[1];
    const int EC = in_sizes[4];
    const int T  = in_sizes[5];
    float* out = (float*)d_out;

    int*    rowcnt   = (int*)d_ws;                              // 1024
    int*    colcnt   = rowcnt + NPART * NCHK;                   // 1024
    int*    gcnt     = colcnt + NPART * NCHK;                   // 512
    float*  good_buf = (float*)(gcnt + 2 * NGRP);               // NN
    float4* rowseg   = (float4*)(good_buf + NN);                // 1024*SEGCAP
    float4* colseg   = rowseg + (size_t)NPART * NCHK * SEGCAP;  // 1024*SEGCAP
    float4* subseg   = colseg + (size_t)NPART * NCHK * SEGCAP;  // 2*NGRP*GCAP

    seg_k<<<NPART * NCHK, 256, 0, stream>>>(
        edges, weights, stat, edges_c, grdt, rowseg, colseg,
        rowcnt, colcnt, gcnt, E, EC);

    subsplit_k<<<2 * 2 * 16 * NPART, 256, 0, stream>>>(
        rowseg, colseg, rowcnt, colcnt, gcnt, subseg);

    colgood_k<<<NGRP, 256, 0, stream>>>(subseg, gcnt, good_buf,
                                        out + 1 + NN);

    rowfair_k<<<NGRP + 1, 256, 0, stream>>>(subseg, gcnt, good_buf,
                                            targets, T, out);
}

// Round 17
// 52.610 us; speedup vs baseline: 4.0302x; 1.2995x over previous
//
#include <hip/hip_runtime.h>
#include <math.h>

#define NN 4096
#define NPART 8              // XCD partitions (blockIdx%8 -> XCD round-robin)
#define NCHK 128             // input chunks
#define GR 16                // rows (cols) per group
#define NGRP 256             // groups per side
#define SCAP 32              // per-(group,chunk) slot capacity (mean 10, >6 sigma)
#define HS 2048              // group hash slots (load ~62%)

// mysign(|v|) - 0.5 with reference-faithful overflow: e=inf -> NaN
__device__ __forceinline__ float smh(float v) {
    float e = expf(6.0f * fabsf(v));
    return 0.5f * (e - 1.0f) / (e + 1.0f);
}

// Phase 1: block (p = blockIdx&7, chunk = blockIdx>>3) scans its chunk and
// keeps records whose row (col) lies in partition p, stashing them into 64
// per-group LDS stashes (~640 low-contention LDS atomics/block). Flush goes
// to FIXED per-(group,chunk) slots with plain-stored counts: no global
// atomics, no zero-init anywhere. XCD-local writes (p = blockIdx&7).
__global__ __launch_bounds__(256) void split_k(
    const long* __restrict__ edges, const float* __restrict__ weights,
    const float* __restrict__ stat, const long* __restrict__ edges_c,
    const float* __restrict__ grdt, float4* __restrict__ subseg,
    int* __restrict__ scnt, int E, int EC) {
    __shared__ float4 stash[64][SCAP];
    __shared__ int cnt[64];
    const int tid = threadIdx.x;
    if (tid < 64) cnt[tid] = 0;
    __syncthreads();
    const int p = blockIdx.x & (NPART - 1);
    const int chunk = blockIdx.x >> 3;
    const int total = E + EC;
    const int csz = (total + NCHK - 1) / NCHK;
    const int lo = chunk * csz;
    const int hi = min(lo + csz, total);
    for (int i = lo + tid; i < hi; i += 256) {
        long e; int isC;
        if (i < E) { e = edges[i]; isC = 0; }
        else { e = edges_c[i - E]; isC = 1; }
        int r = (int)e;              // little-endian: x = low 32 bits
        int c = (int)(e >> 32);
        bool rowHit = (r >> 9) == p;
        bool colHit = (c >> 9) == p;
        if (!rowHit && !colHit) continue;
        float4 rec;
        rec.x = __int_as_float((c << 13) | (r << 1) | isC);
        if (isC) { rec.y = grdt[i - E]; rec.z = 0.f; }
        else { rec.y = stat[i]; rec.z = weights[i]; }
        rec.w = 0.f;
        if (rowHit) {
            int s = (r >> 4) & 31;
            int pos = atomicAdd(&cnt[s], 1);       // LDS, 64-way spread
            if (pos < SCAP) stash[s][pos] = rec;
        }
        if (colHit) {
            int s = 32 + ((c >> 4) & 31);
            int pos = atomicAdd(&cnt[s], 1);
            if (pos < SCAP) stash[s][pos] = rec;
        }
    }
    __syncthreads();
    // flat parallel flush: consecutive tid -> consecutive slot (coalesced)
    for (int idx = tid; idx < 64 * SCAP; idx += 256) {
        int s = idx >> 5, i = idx & (SCAP - 1);
        if (i < cnt[s]) {
            int side = s >> 5;
            int grp = p * 32 + (s & 31);
            subseg[(((size_t)side * NGRP + grp) * NCHK + chunk) * SCAP + i]
                = stash[s][i];
        }
    }
    if (tid < 64) {
        int side = tid >> 5;
        int grp = p * 32 + (tid & 31);
        scnt[(side * NGRP + grp) * NCHK + chunk] = min(cnt[tid], SCAP);
    }
}

// Phase 2a: block per 16-col group; reads exactly its group's 128 chunk
// mini-segments (thread-per-chunk). LDS hash coalesces duplicate cells
// (scatter-add semantics like the reference); sweep v = B*(A-1)+A*W:
// g += v, nin += smh(v); good = clip(g/Nin,-1,1) NaN-propagating, Nin
// baseline 2048 (mysign(0)=0.5 per zero cell). XCD-local (blockIdx&7 = p).
__global__ __launch_bounds__(512) void colgood_k(
    const float4* __restrict__ subseg, const int* __restrict__ scnt,
    float* __restrict__ good_buf, float* __restrict__ good_out) {
    __shared__ int hkey[HS];
    __shared__ float hA[HS], hW[HS], hB[HS];
    __shared__ int s_cnt[NCHK];
    __shared__ float a1[GR], a2[GR];
    const int tid = threadIdx.x;
    const int g = (blockIdx.x & 7) * 32 + (blockIdx.x >> 3);
    const int cb = g * GR;
    for (int i = tid; i < HS; i += 512) {
        hkey[i] = -1; hA[i] = 0.f; hW[i] = 0.f; hB[i] = 0.f;
    }
    if (tid < NCHK) s_cnt[tid] = scnt[(NGRP + g) * NCHK + tid];
    if (tid < GR) { a1[tid] = 0.f; a2[tid] = 0.f; }
    __syncthreads();
    {   // thread (chunk = tid&127, sub = tid>>7) inserts its share
        const int chunk = tid & (NCHK - 1);
        const int sub = tid >> 7;              // 0..3
        const int n = s_cnt[chunk];
        const float4* sp = subseg
            + (((size_t)NGRP + g) * NCHK + chunk) * SCAP;
        for (int i = sub; i < n; i += 4) {
            float4 rec = sp[i];
            int ct = __float_as_int(rec.x);
            int c = ct >> 13;
            int r = (ct >> 1) & 4095;
            int key = ((c - cb) << 12) | r;
            int slot = (int)(((unsigned)key * 2654435761u) >> 21) & (HS - 1);
            while (true) {
                int prev = atomicCAS(&hkey[slot], -1, key);
                if (prev == -1 || prev == key) break;
                slot = (slot + 1) & (HS - 1);
            }
            if (ct & 1) {
                atomicAdd(&hB[slot], rec.y);
            } else {
                atomicAdd(&hA[slot], rec.y);
                atomicAdd(&hW[slot], rec.z);
            }
        }
    }
    __syncthreads();
#pragma unroll
    for (int k = 0; k < HS / 512; ++k) {       // 4 slots/thread
        int s = k * 512 + tid;
        int key = hkey[s];
        if (key != -1) {
            float a = hA[s], w = hW[s], b = hB[s];
            float v = b * (a - 1.0f) + a * w;
            if (v != 0.0f) {                   // zero cells: 0 to all sums
                int d = key >> 12;
                atomicAdd(&a1[d], smh(v));     // NaN propagates like ref
                atomicAdd(&a2[d], v);          // g (column sum)
            }
        }
    }
    __syncthreads();
    if (tid < GR) {
        float Nin = 2048.0f + a1[tid];
        float gd = 1.0f;
        if (Nin != 0.0f) {
            float x = a2[tid] / Nin;
            gd = x < -1.0f ? -1.0f : (x > 1.0f ? 1.0f : x);  // NaN stays NaN
        }
        good_buf[cb + tid] = gd;
        good_out[cb + tid] = gd;
    }
}

// Phase 2b: block per 16-row group; same structure; fair computed inline
// (good_buf final): f += 1 - |v - good[c]|/2 over v != 0;
// fair = clip(f/Nout, 0, 1). Last block does the targets gsum.
__global__ __launch_bounds__(512) void rowfair_k(
    const float4* __restrict__ subseg, const int* __restrict__ scnt,
    const float* __restrict__ good_buf, const int* __restrict__ targets,
    int T, float* __restrict__ out) {
    if (blockIdx.x < NGRP) {
        __shared__ int hkey[HS];
        __shared__ float hA[HS], hW[HS], hB[HS];
        __shared__ int s_cnt[NCHK];
        __shared__ float a1[GR], a2[GR];
        const int tid = threadIdx.x;
        const int g = (blockIdx.x & 7) * 32 + (blockIdx.x >> 3);
        const int rb = g * GR;
        for (int i = tid; i < HS; i += 512) {
            hkey[i] = -1; hA[i] = 0.f; hW[i] = 0.f; hB[i] = 0.f;
        }
        if (tid < NCHK) s_cnt[tid] = scnt[g * NCHK + tid];
        if (tid < GR) { a1[tid] = 0.f; a2[tid] = 0.f; }
        __syncthreads();
        {
            const int chunk = tid & (NCHK - 1);
            const int sub = tid >> 7;
            const int n = s_cnt[chunk];
            const float4* sp = subseg + ((size_t)g * NCHK + chunk) * SCAP;
            for (int i = sub; i < n; i += 4) {
                float4 rec = sp[i];
                int ct = __float_as_int(rec.x);
                int c = ct >> 13;
                int r = (ct >> 1) & 4095;
                int key = ((r - rb) << 12) | c;
                int slot = (int)(((unsigned)key * 2654435761u) >> 21) & (HS - 1);
                while (true) {
                    int prev = atomicCAS(&hkey[slot], -1, key);
                    if (prev == -1 || prev == key) break;
                    slot = (slot + 1) & (HS - 1);
                }
                if (ct & 1) {
                    atomicAdd(&hB[slot], rec.y);
                } else {
                    atomicAdd(&hA[slot], rec.y);
                    atomicAdd(&hW[slot], rec.z);
                }
            }
        }
        __syncthreads();
#pragma unroll
        for (int k = 0; k < HS / 512; ++k) {   // 4 slots/thread
            int s = k * 512 + tid;
            int key = hkey[s];
            if (key != -1) {
                float a = hA[s], w = hW[s], b = hB[s];
                float v = b * (a - 1.0f) + a * w;
                if (v != 0.0f) {               // reference mask: V != 0
                    int d = key >> 12;
                    atomicAdd(&a1[d], smh(v)); // NaN propagates
                    atomicAdd(&a2[d],
                              1.0f - 0.5f * fabsf(v - good_buf[key & 4095]));
                }
            }
        }
        __syncthreads();
        if (tid < GR) {
            float Nout = 2048.0f + a1[tid];
            float fair = 1.0f;
            if (Nout != 0.0f) {
                float x = a2[tid] / Nout;
                fair = x < 0.0f ? 0.0f : (x > 1.0f ? 1.0f : x);  // NaN stays
            }
            out[1 + rb + tid] = fair;
        }
    } else {
        float s = 0.f;
        for (int i = threadIdx.x; i < T; i += 512) {
            float gt = good_buf[targets[i]];
            s += (gt == gt) ? gt : 0.0f;       // NaN -> 0
        }
        for (int off = 32; off > 0; off >>= 1) s += __shfl_down(s, off, 64);
        __shared__ float lds[8];
        int lane = threadIdx.x & 63, w = threadIdx.x >> 6;
        if (lane == 0) lds[w] = s;
        __syncthreads();
        if (threadIdx.x == 0) {
            float tot = 0.f;
            for (int i = 0; i < 8; ++i) tot += lds[i];
            out[0] = tot;
        }
    }
}

extern "C" void kernel_launch(void* const* d_in, const int* in_sizes, int n_in,
                              void* d_out, int out_size, void* d_ws, size_t ws_size,
                              hipStream_t stream) {
    const long*  edges   = (const long*)d_in[0];
    const float* weights = (const float*)d_in[1];
    const float* stat    = (const float*)d_in[2];
    const long*  edges_c = (const long*)d_in[3];
    const float* grdt    = (const float*)d_in[4];
    const int*   targets = (const int*)d_in[5];
    const int E  = in_sizes[1];
    const int EC = in_sizes[4];
    const int T  = in_sizes[5];
    float* out = (float*)d_out;

    int*    scnt     = (int*)d_ws;                       // 2*NGRP*NCHK
    float*  good_buf = (float*)(scnt + 2 * NGRP * NCHK); // NN
    float4* subseg   = (float4*)(good_buf + NN);         // 2*NGRP*NCHK*SCAP

    split_k<<<NPART * NCHK, 256, 0, stream>>>(
        edges, weights, stat, edges_c, grdt, subseg, scnt, E, EC);

    colgood_k<<<NGRP, 512, 0, stream>>>(subseg, scnt, good_buf,
                                        out + 1 + NN);

    rowfair_k<<<NGRP + 1, 512, 0, stream>>>(subseg, scnt, good_buf,
                                            targets, T, out);
}

// Round 18
// 36.388 us; speedup vs baseline: 5.8270x; 1.4458x over previous
//
#include <hip/hip_runtime.h>
#include <math.h>

#define NN 4096
#define NPART 8              // XCD partitions (blockIdx%8 -> XCD round-robin)
#define NCHK 128             // input chunks
#define GR 16                // rows (cols) per group
#define NGRP 256             // groups per side
#define SCAP 32              // per-(group,chunk) slot capacity (mean 10, >6 sigma)
#define HS 4096              // group hash slots (load ~31%, ~1.2 probes)
#define NW 16                // waves per phase-2 block (1024 threads)

// mysign(|v|) - 0.5 with reference-faithful overflow: e=inf -> NaN
__device__ __forceinline__ float smh(float v) {
    float e = expf(6.0f * fabsf(v));
    return 0.5f * (e - 1.0f) / (e + 1.0f);
}

// Phase 1: block (p = blockIdx&7, chunk = blockIdx>>3) scans its chunk and
// keeps records whose row (col) lies in partition p, stashing them into 64
// per-group LDS stashes. Flush goes to FIXED per-(group,chunk) slots with
// plain-stored counts: no global atomics, no zero-init anywhere. XCD-local
// writes (p = blockIdx&7). 512 threads: 4 blocks/CU (LDS-capped) = 2048
// resident threads/CU, double round-17's occupancy.
__global__ __launch_bounds__(512) void split_k(
    const long* __restrict__ edges, const float* __restrict__ weights,
    const float* __restrict__ stat, const long* __restrict__ edges_c,
    const float* __restrict__ grdt, float4* __restrict__ subseg,
    int* __restrict__ scnt, int E, int EC) {
    __shared__ float4 stash[64][SCAP];
    __shared__ int cnt[64];
    const int tid = threadIdx.x;
    if (tid < 64) cnt[tid] = 0;
    __syncthreads();
    const int p = blockIdx.x & (NPART - 1);
    const int chunk = blockIdx.x >> 3;
    const int total = E + EC;
    const int csz = (total + NCHK - 1) / NCHK;
    const int lo = chunk * csz;
    const int hi = min(lo + csz, total);
    for (int i = lo + tid; i < hi; i += 512) {
        long e; int isC;
        if (i < E) { e = edges[i]; isC = 0; }
        else { e = edges_c[i - E]; isC = 1; }
        int r = (int)e;              // little-endian: x = low 32 bits
        int c = (int)(e >> 32);
        bool rowHit = (r >> 9) == p;
        bool colHit = (c >> 9) == p;
        if (!rowHit && !colHit) continue;
        float4 rec;
        rec.x = __int_as_float((c << 13) | (r << 1) | isC);
        if (isC) { rec.y = grdt[i - E]; rec.z = 0.f; }
        else { rec.y = stat[i]; rec.z = weights[i]; }
        rec.w = 0.f;
        if (rowHit) {
            int s = (r >> 4) & 31;
            int pos = atomicAdd(&cnt[s], 1);       // LDS, 64-way spread
            if (pos < SCAP) stash[s][pos] = rec;
        }
        if (colHit) {
            int s = 32 + ((c >> 4) & 31);
            int pos = atomicAdd(&cnt[s], 1);
            if (pos < SCAP) stash[s][pos] = rec;
        }
    }
    __syncthreads();
    // flat parallel flush: consecutive tid -> consecutive slot (coalesced)
    for (int idx = tid; idx < 64 * SCAP; idx += 512) {
        int s = idx >> 5, i = idx & (SCAP - 1);
        if (i < cnt[s]) {
            int side = s >> 5;
            int grp = p * 32 + (s & 31);
            subseg[(((size_t)side * NGRP + grp) * NCHK + chunk) * SCAP + i]
                = stash[s][i];
        }
    }
    if (tid < 64) {
        int side = tid >> 5;
        int grp = p * 32 + (tid & 31);
        scnt[(side * NGRP + grp) * NCHK + chunk] = min(cnt[tid], SCAP);
    }
}

// Phase 2a: block per 16-col group; reads exactly its group's 128 chunk
// mini-segments. LDS hash (4096 slots, ~31% load) coalesces duplicate cells
// (scatter-add semantics like the reference); sweep v = B*(A-1)+A*W with
// per-wave accumulator columns (no 16-scalar contention); good =
// clip(g/Nin,-1,1) NaN-propagating, Nin baseline 2048 (mysign(0)=0.5 per
// zero cell). 1024 threads; grid 256 = 1 block/CU so big LDS is free.
__global__ __launch_bounds__(1024) void colgood_k(
    const float4* __restrict__ subseg, const int* __restrict__ scnt,
    float* __restrict__ good_buf, float* __restrict__ good_out) {
    __shared__ int hkey[HS];
    __shared__ float hA[HS], hW[HS], hB[HS];
    __shared__ int s_cnt[NCHK];
    __shared__ float a1[GR][NW + 1], a2[GR][NW + 1];
    const int tid = threadIdx.x;
    const int wv = tid >> 6;
    const int g = (blockIdx.x & 7) * 32 + (blockIdx.x >> 3);
    const int cb = g * GR;
    for (int i = tid; i < HS; i += 1024) {
        hkey[i] = -1; hA[i] = 0.f; hW[i] = 0.f; hB[i] = 0.f;
    }
    if (tid < NCHK) s_cnt[tid] = scnt[(NGRP + g) * NCHK + tid];
    if (tid < GR * (NW + 1)) {
        ((float*)a1)[tid] = 0.f;
        ((float*)a2)[tid] = 0.f;
    }
    __syncthreads();
    {   // thread (chunk = tid&127, sub = tid>>7) inserts its share
        const int chunk = tid & (NCHK - 1);
        const int sub = tid >> 7;              // 0..7
        const int n = s_cnt[chunk];
        const float4* sp = subseg
            + (((size_t)NGRP + g) * NCHK + chunk) * SCAP;
        for (int i = sub; i < n; i += 8) {
            float4 rec = sp[i];
            int ct = __float_as_int(rec.x);
            int c = ct >> 13;
            int r = (ct >> 1) & 4095;
            int key = ((c - cb) << 12) | r;
            int slot = (int)(((unsigned)key * 2654435761u) >> 20) & (HS - 1);
            while (true) {
                int prev = atomicCAS(&hkey[slot], -1, key);
                if (prev == -1 || prev == key) break;
                slot = (slot + 1) & (HS - 1);
            }
            if (ct & 1) {
                atomicAdd(&hB[slot], rec.y);
            } else {
                atomicAdd(&hA[slot], rec.y);
                atomicAdd(&hW[slot], rec.z);
            }
        }
    }
    __syncthreads();
#pragma unroll
    for (int k = 0; k < HS / 1024; ++k) {      // 4 slots/thread
        int s = k * 1024 + tid;
        int key = hkey[s];
        if (key != -1) {
            float a = hA[s], w = hW[s], b = hB[s];
            float v = b * (a - 1.0f) + a * w;
            if (v != 0.0f) {                   // zero cells: 0 to all sums
                int d = key >> 12;
                atomicAdd(&a1[d][wv], smh(v)); // NaN propagates like ref
                atomicAdd(&a2[d][wv], v);      // g (column sum)
            }
        }
    }
    __syncthreads();
    if (tid < GR) {
        float nin = 0.f, gsum = 0.f;
        for (int w = 0; w < NW; ++w) { nin += a1[tid][w]; gsum += a2[tid][w]; }
        float Nin = 2048.0f + nin;
        float gd = 1.0f;
        if (Nin != 0.0f) {
            float x = gsum / Nin;
            gd = x < -1.0f ? -1.0f : (x > 1.0f ? 1.0f : x);  // NaN stays NaN
        }
        good_buf[cb + tid] = gd;
        good_out[cb + tid] = gd;
    }
}

// Phase 2b: block per 16-row group; same structure; fair computed inline
// (good_buf final): f += 1 - |v - good[c]|/2 over v != 0;
// fair = clip(f/Nout, 0, 1). Last block does the targets gsum.
__global__ __launch_bounds__(1024) void rowfair_k(
    const float4* __restrict__ subseg, const int* __restrict__ scnt,
    const float* __restrict__ good_buf, const int* __restrict__ targets,
    int T, float* __restrict__ out) {
    if (blockIdx.x < NGRP) {
        __shared__ int hkey[HS];
        __shared__ float hA[HS], hW[HS], hB[HS];
        __shared__ int s_cnt[NCHK];
        __shared__ float a1[GR][NW + 1], a2[GR][NW + 1];
        const int tid = threadIdx.x;
        const int wv = tid >> 6;
        const int g = (blockIdx.x & 7) * 32 + (blockIdx.x >> 3);
        const int rb = g * GR;
        for (int i = tid; i < HS; i += 1024) {
            hkey[i] = -1; hA[i] = 0.f; hW[i] = 0.f; hB[i] = 0.f;
        }
        if (tid < NCHK) s_cnt[tid] = scnt[g * NCHK + tid];
        if (tid < GR * (NW + 1)) {
            ((float*)a1)[tid] = 0.f;
            ((float*)a2)[tid] = 0.f;
        }
        __syncthreads();
        {
            const int chunk = tid & (NCHK - 1);
            const int sub = tid >> 7;          // 0..7
            const int n = s_cnt[chunk];
            const float4* sp = subseg + ((size_t)g * NCHK + chunk) * SCAP;
            for (int i = sub; i < n; i += 8) {
                float4 rec = sp[i];
                int ct = __float_as_int(rec.x);
                int c = ct >> 13;
                int r = (ct >> 1) & 4095;
                int key = ((r - rb) << 12) | c;
                int slot = (int)(((unsigned)key * 2654435761u) >> 20) & (HS - 1);
                while (true) {
                    int prev = atomicCAS(&hkey[slot], -1, key);
                    if (prev == -1 || prev == key) break;
                    slot = (slot + 1) & (HS - 1);
                }
                if (ct & 1) {
                    atomicAdd(&hB[slot], rec.y);
                } else {
                    atomicAdd(&hA[slot], rec.y);
                    atomicAdd(&hW[slot], rec.z);
                }
            }
        }
        __syncthreads();
#pragma unroll
        for (int k = 0; k < HS / 1024; ++k) {  // 4 slots/thread
            int s = k * 1024 + tid;
            int key = hkey[s];
            if (key != -1) {
                float a = hA[s], w = hW[s], b = hB[s];
                float v = b * (a - 1.0f) + a * w;
                if (v != 0.0f) {               // reference mask: V != 0
                    int d = key >> 12;
                    atomicAdd(&a1[d][wv], smh(v));  // NaN propagates
                    atomicAdd(&a2[d][wv],
                              1.0f - 0.5f * fabsf(v - good_buf[key & 4095]));
                }
            }
        }
        __syncthreads();
        if (tid < GR) {
            float nout = 0.f, f = 0.f;
            for (int w = 0; w < NW; ++w) { nout += a1[tid][w]; f += a2[tid][w]; }
            float Nout = 2048.0f + nout;
            float fair = 1.0f;
            if (Nout != 0.0f) {
                float x = f / Nout;
                fair = x < 0.0f ? 0.0f : (x > 1.0f ? 1.0f : x);  // NaN stays
            }
            out[1 + rb + tid] = fair;
        }
    } else {
        float s = 0.f;
        for (int i = threadIdx.x; i < T; i += 1024) {
            float gt = good_buf[targets[i]];
            s += (gt == gt) ? gt : 0.0f;       // NaN -> 0
        }
        for (int off = 32; off > 0; off >>= 1) s += __shfl_down(s, off, 64);
        __shared__ float lds[NW];
        int lane = threadIdx.x & 63, w = threadIdx.x >> 6;
        if (lane == 0) lds[w] = s;
        __syncthreads();
        if (threadIdx.x == 0) {
            float tot = 0.f;
            for (int i = 0; i < NW; ++i) tot += lds[i];
            out[0] = tot;
        }
    }
}

extern "C" void kernel_launch(void* const* d_in, const int* in_sizes, int n_in,
                              void* d_out, int out_size, void* d_ws, size_t ws_size,
                              hipStream_t stream) {
    const long*  edges   = (const long*)d_in[0];
    const float* weights = (const float*)d_in[1];
    const float* stat    = (const float*)d_in[2];
    const long*  edges_c = (const long*)d_in[3];
    const float* grdt    = (const float*)d_in[4];
    const int*   targets = (const int*)d_in[5];
    const int E  = in_sizes[1];
    const int EC = in_sizes[4];
    const int T  = in_sizes[5];
    float* out = (float*)d_out;

    int*    scnt     = (int*)d_ws;                       // 2*NGRP*NCHK
    float*  good_buf = (float*)(scnt + 2 * NGRP * NCHK); // NN
    float4* subseg   = (float4*)(good_buf + NN);         // 2*NGRP*NCHK*SCAP

    split_k<<<NPART * NCHK, 512, 0, stream>>>(
        edges, weights, stat, edges_c, grdt, subseg, scnt, E, EC);

    colgood_k<<<NGRP, 1024, 0, stream>>>(subseg, scnt, good_buf,
                                         out + 1 + NN);

    rowfair_k<<<NGRP + 1, 1024, 0, stream>>>(subseg, scnt, good_buf,
                                             targets, T, out);
}